// Round 8
// baseline (258.198 us; speedup 1.0000x reference)
//
#include <hip/hip_runtime.h>
#include <hip/hip_fp16.h>
#include <stdint.h>

#define NCTX 5952
#define NHEAD 16

// contiguous workspace layout (bytes); shared by launcher and kernels
#define SZ_A  12189696u          // 5952*1024*2
#define SZ_W   8388608u          // 4096*1024*2
#define OFF_AH  0u
#define OFF_AL  (OFF_AH + SZ_A)
#define OFF_WH  (OFF_AL + SZ_A)
#define OFF_WL  (OFF_WH + SZ_W)
#define OFF_AHC (OFF_WL + SZ_W)
#define OFF_ALC (OFF_AHC + SZ_A)
#define OFF_QH  (OFF_ALC + SZ_A)
#define OFF_KH  (OFF_QH + SZ_A)
#define OFF_VT  (OFF_KH + SZ_A)

typedef _Float16 f16x8 __attribute__((ext_vector_type(8)));
typedef _Float16 f16x4 __attribute__((ext_vector_type(4)));
typedef float    f32x4 __attribute__((ext_vector_type(4)));
typedef float    f32x16 __attribute__((ext_vector_type(16)));

typedef const __attribute__((address_space(1))) void* gp1;
typedef __attribute__((address_space(3))) void* lp3;

__device__ __forceinline__ f32x4 mfma16(f16x8 a, f16x8 b, f32x4 c) {
    return __builtin_amdgcn_mfma_f32_16x16x32_f16(a, b, c, 0, 0, 0);
}
__device__ __forceinline__ f32x16 mfma32(f16x8 a, f16x8 b, f32x16 c) {
    return __builtin_amdgcn_mfma_f32_32x32x16_f16(a, b, c, 0, 0, 0);
}

// per-seq tables: lengths {512,576,640,704,768,832,896,1024}
__device__ const int kQT[9]    = {0, 4, 9, 14, 20, 26, 33, 40, 48};
__device__ const int kBASE8[8] = {0, 512, 1088, 1728, 2432, 3200, 4032, 4928};
__device__ const int kLEN[8]   = {512, 576, 640, 704, 768, 832, 896, 1024};

// ---- fused pre-split: fp32 -> f16 hi/lo plain row-major arrays ----
__global__ __launch_bounds__(256) void presplit_all(
    const float* __restrict__ x,
    const float* __restrict__ Wq, const float* __restrict__ Wk,
    const float* __restrict__ Wv, const float* __restrict__ Wo,
    _Float16* __restrict__ Ah, _Float16* __restrict__ Al,
    _Float16* __restrict__ Wh, _Float16* __restrict__ Wl)
{
    constexpr int NA = NCTX * 128 / 256;   // 2976
    const int bid = blockIdx.x;
    const float* src;
    _Float16 *dh, *dl;
    size_t off;
    if (bid < NA) {
        int idx = bid * 256 + threadIdx.x;
        int m = idx >> 7, k8 = (idx & 127) << 3;
        src = x + (size_t)m * 1024 + k8;
        off = (size_t)m * 1024 + k8;
        dh = Ah; dl = Al;
    } else {
        int idx = (bid - NA) * 256 + threadIdx.x;
        int n = idx >> 7, k8 = (idx & 127) << 3;
        const float* s = (n < 1024) ? Wq : (n < 2048) ? Wk : (n < 3072) ? Wv : Wo;
        src = s + (size_t)(n & 1023) * 1024 + k8;
        off = (size_t)n * 1024 + k8;
        dh = Wh; dl = Wl;
    }
    f16x8 hi, lo;
    #pragma unroll
    for (int e = 0; e < 8; ++e) {
        float v = src[e];
        _Float16 h = (_Float16)v;
        hi[e] = h; lo[e] = (_Float16)(v - (float)h);
    }
    *(f16x8*)&dh[off] = hi;
    *(f16x8*)&dl[off] = lo;
}

// ---- 3-pairing split GEMM on 32x32x16 MFMA: C = Ah*Bh + Ah*Bl + Al*Bh ----
// BM=192, per-wave 96x96 (MODE0) / 96x32 (MODE1); K=1024, BK=32, T=32 steps.
// MODE 0: BN=384, grid 31x8=248, q/k/v epilogue.  MODE 1: BN=128, grid 31x8=248.
// 2 LDS buffers; step t stages tile t+1 into the other buffer at step top
// (whole step ~3.5k cyc hides the DMA); read-ahead: each read cluster is
// issued before the previous MFMA cluster so it drains under the matrix pipe.
template <int MODE>
__global__ __launch_bounds__(512, 2) void gemm32(
    const char* __restrict__ ws,
    const float* __restrict__ bq, const float* __restrict__ bv, const float* __restrict__ bo,
    float* __restrict__ outp)
{
    constexpr int BN   = (MODE == 0) ? 384 : 128;
    constexpr int NFR  = (MODE == 0) ? 3 : 1;     // 32-col frags per wave
    constexpr int nB   = BN / 16;                 // 24 / 8
    constexpr int SPW  = (24 + 2 * nB) / 8;       // 9 / 5 stage instrs per wave
    constexpr int ABYT = 192 * 64;                // 12288
    constexpr int BBYT = BN * 64;                 // 24576 / 8192
    constexpr int BUF  = 2 * ABYT + 2 * BBYT;     // 73728 / 40960
    constexpr int T    = 32;
    constexpr int W0   = (MODE == 0) ? 0 : 3072;

    __shared__ alignas(16) char lds[2 * BUF];

    int bid = blockIdx.x;
    bid = (bid & 7) * 31 + (bid >> 3);            // bijective XCD swizzle (248=8*31)
    const int mt = bid / 8, nt = bid % 8;
    const int m0 = mt * 192, n0 = nt * BN;
    const int tid = threadIdx.x;
    const int w = tid >> 6, l = tid & 63;
    const int h = l >> 5, r5 = l & 31;
    const int wm = w >> 2, wn = w & 3;

    // ---- staging setup: linear LDS dest, inverse-swizzled global source ----
    const int laneOff = (l >> 2) * 2048 + 16 * ((l & 3) ^ ((l >> 3) & 3));
    const char* wsl = ws + laneOff;
    const uint32_t A_OFF = (MODE ? OFF_AHC : OFF_AH) + (uint32_t)m0 * 2048u;
    const uint32_t W_OFF = OFF_WH + (uint32_t)(W0 + n0) * 2048u;
    uint32_t off[SPW]; int ldst[SPW];
    #pragma unroll
    for (int s = 0; s < SPW; ++s) {
        int f = w * SPW + s;
        uint32_t roff;
        if (f < 12)           roff = A_OFF + (uint32_t)f * 32768u;
        else if (f < 24)      roff = A_OFF + SZ_A + (uint32_t)(f - 12) * 32768u;
        else if (f < 24 + nB) roff = W_OFF + (uint32_t)(f - 24) * 32768u;
        else                  roff = W_OFF + SZ_W + (uint32_t)(f - 24 - nB) * 32768u;
        off[s] = roff;
        ldst[s] = f * 1024;
    }
    auto STG = [&](int buf, int t2) {
        #pragma unroll
        for (int s = 0; s < SPW; ++s)
            __builtin_amdgcn_global_load_lds((gp1)(wsl + off[s] + (uint32_t)t2 * 64u),
                                             (lp3)(lds + buf * BUF + ldst[s]), 16, 0, 0);
    };

    // ---- fragment LDS byte offsets (granule-swizzled reads) ----
    const int sg = (r5 >> 1) & 3;
    int aoA[3][2], aoB[NFR][2];
    #pragma unroll
    for (int i = 0; i < 3; ++i)
        #pragma unroll
        for (int s = 0; s < 2; ++s) {
            int r = wm * 96 + i * 32 + r5;
            aoA[i][s] = r * 64 + 16 * (((s << 1) + h) ^ sg);
        }
    #pragma unroll
    for (int j = 0; j < NFR; ++j)
        #pragma unroll
        for (int s = 0; s < 2; ++s) {
            int r = wn * (32 * NFR) + j * 32 + r5;
            aoB[j][s] = r * 64 + 16 * (((s << 1) + h) ^ sg);
        }

    f32x16 acc[3][NFR] = {};

    // prologue: stage tile 0 -> buf 0
    STG(0, 0);
    asm volatile("s_waitcnt vmcnt(0)" ::: "memory");
    __builtin_amdgcn_s_barrier();

    #pragma unroll 1
    for (int t = 0; t < T; ++t) {
        const int cb = t & 1;
        const char* cbp = lds + cb * BUF;
        auto rdAh = [&](int i, int s) { return *(const f16x8*)(cbp + aoA[i][s]); };
        auto rdAl = [&](int i, int s) { return *(const f16x8*)(cbp + ABYT + aoA[i][s]); };
        auto rdBh = [&](int j, int s) { return *(const f16x8*)(cbp + 2 * ABYT + aoB[j][s]); };
        auto rdBl = [&](int j, int s) { return *(const f16x8*)(cbp + 2 * ABYT + BBYT + aoB[j][s]); };
        auto MM = [&](f16x8 (&A)[3], f16x8 (&B)[NFR]) {
            __builtin_amdgcn_s_setprio(1);
            #pragma unroll
            for (int i = 0; i < 3; ++i)
                #pragma unroll
                for (int j = 0; j < NFR; ++j)
                    acc[i][j] = mfma32(A[i], B[j], acc[i][j]);
            __builtin_amdgcn_s_setprio(0);
        };

        if (t + 1 < T) STG(1 - cb, t + 1);      // DMA hides under this whole step

        f16x8 ah0[3], al0[3], bh0[NFR], bl0[NFR];
        f16x8 ah1[3], al1[3], bh1[NFR], bl1[NFR];
        #pragma unroll
        for (int i = 0; i < 3; ++i) ah0[i] = rdAh(i, 0);
        #pragma unroll
        for (int j = 0; j < NFR; ++j) bh0[j] = rdBh(j, 0);
        #pragma unroll
        for (int j = 0; j < NFR; ++j) bl0[j] = rdBl(j, 0);
        MM(ah0, bh0);                            // hh0
        #pragma unroll
        for (int i = 0; i < 3; ++i) al0[i] = rdAl(i, 0);
        MM(ah0, bl0);                            // hl0
        #pragma unroll
        for (int i = 0; i < 3; ++i) ah1[i] = rdAh(i, 1);
        #pragma unroll
        for (int j = 0; j < NFR; ++j) bh1[j] = rdBh(j, 1);
        MM(al0, bh0);                            // lh0
        #pragma unroll
        for (int j = 0; j < NFR; ++j) bl1[j] = rdBl(j, 1);
        MM(ah1, bh1);                            // hh1
        #pragma unroll
        for (int i = 0; i < 3; ++i) al1[i] = rdAl(i, 1);
        MM(ah1, bl1);                            // hl1
        MM(al1, bh1);                            // lh1

        // tile t+1 DMA landed (issued ~1 step ago); own ds_reads all consumed
        asm volatile("s_waitcnt vmcnt(0) lgkmcnt(0)" ::: "memory");
        __builtin_amdgcn_s_barrier();
    }

    // ---- epilogue. 32x32 C/D: col = lane&31, row = (reg&3)+8*(reg>>2)+4*(lane>>5) ----
    char* wsm = (char*)ws;   // outputs live in ws too
    _Float16* qh = (_Float16*)(wsm + OFF_QH);
    _Float16* kh = (_Float16*)(wsm + OFF_KH);
    _Float16* vt = (_Float16*)(wsm + OFF_VT);
    #pragma unroll
    for (int i = 0; i < 3; ++i)
        #pragma unroll
        for (int j = 0; j < NFR; ++j) {
            const int mbase = m0 + wm * 96 + i * 32 + 4 * h;
            const int n = n0 + wn * (32 * NFR) + j * 32 + r5;
            if (MODE == 0) {
                const int which = n >> 10, nn = n & 1023;
                const int hh = nn >> 6, dd = nn & 63;
                if (which == 2) {
                    const float bb = bv[nn];
                    #pragma unroll
                    for (int rq = 0; rq < 4; ++rq) {
                        f16x4 v4;
                        #pragma unroll
                        for (int e = 0; e < 4; ++e) v4[e] = (_Float16)(acc[i][j][rq * 4 + e] + bb);
                        *(f16x4*)&vt[((size_t)hh * 64 + dd) * NCTX + mbase + 8 * rq] = v4;  // d-major
                    }
                } else if (which == 0) {
                    const float bb = bq[nn];
                    #pragma unroll
                    for (int r = 0; r < 16; ++r) {
                        const int m = mbase + (r & 3) + 8 * (r >> 2);
                        qh[((size_t)hh * NCTX + m) * 64 + dd] = (_Float16)(acc[i][j][r] + bb);
                    }
                } else {
                    #pragma unroll
                    for (int r = 0; r < 16; ++r) {
                        const int m = mbase + (r & 3) + 8 * (r >> 2);
                        kh[((size_t)hh * NCTX + m) * 64 + dd] = (_Float16)acc[i][j][r];
                    }
                }
            } else {
                const float bb = bo[n];
                #pragma unroll
                for (int r = 0; r < 16; ++r) {
                    const int m = mbase + (r & 3) + 8 * (r >> 2);
                    outp[(size_t)m * 1024 + n] = acc[i][j][r] + bb;
                }
            }
        }
}

// ---- flash attention (no-max), 4 waves x 32 q-rows per 128-row tile ----
__global__ __launch_bounds__(256) void attn_kernel(
    const _Float16* __restrict__ qh, const _Float16* __restrict__ kh,
    const _Float16* __restrict__ vt,
    _Float16* __restrict__ Ahc, _Float16* __restrict__ Alc)
{
    __shared__ alignas(16) _Float16 P[4][2][16][64];
    const int bid = blockIdx.x;
    const int hd = bid & 15, t = bid >> 4;
    int b = 0;
    while (t >= kQT[b + 1]) ++b;
    const int kbase = kBASE8[b];
    const int L = kLEN[b];
    const int w = threadIdx.x >> 6, l = threadIdx.x & 63;
    const int ls = l >> 4, lq = l & 15;
    const int q0l = (t - kQT[b]) * 128 + w * 32;
    if (q0l >= L) return;          // tail waves of ragged tiles; no barriers below
    const int q0 = kbase + q0l;

    f16x8 qf[2][2];
    #pragma unroll
    for (int qg = 0; qg < 2; ++qg) {
        const _Float16* qp = qh + ((size_t)hd * NCTX + q0 + qg * 16 + lq) * 64 + ls * 8;
        qf[qg][0] = *(const f16x8*)qp;
        qf[qg][1] = *(const f16x8*)(qp + 32);
    }
    const _Float16* kb = kh + (size_t)hd * NCTX * 64;
    const _Float16* vb = vt + (size_t)hd * 64 * NCTX;

    f32x4 acc[2][4] = {};
    float lsum[2] = {0.f, 0.f};

    for (int kv = 0; kv < L; kv += 64) {
        f32x4 s[2][4];
        __builtin_amdgcn_s_setprio(1);
        #pragma unroll
        for (int g = 0; g < 4; ++g) {
            const _Float16* kp = kb + (size_t)(kbase + kv + g * 16 + lq) * 64 + ls * 8;
            f16x8 kf0 = *(const f16x8*)kp;
            f16x8 kf1 = *(const f16x8*)(kp + 32);
            #pragma unroll
            for (int qg = 0; qg < 2; ++qg) {
                f32x4 z = {};
                z = mfma16(kf0, qf[qg][0], z);
                z = mfma16(kf1, qf[qg][1], z);
                s[qg][g] = z;   // S^T: row = key, col = q = lane&15
            }
        }
        __builtin_amdgcn_s_setprio(0);
        #pragma unroll
        for (int qg = 0; qg < 2; ++qg) {
            float tsum = 0.f;
            #pragma unroll
            for (int g = 0; g < 4; ++g) {
                f16x4 ph;
                #pragma unroll
                for (int r = 0; r < 4; ++r) {
                    float pv = __expf(s[qg][g][r] * 0.125f);
                    tsum += pv;
                    ph[r] = (_Float16)pv;
                }
                int gi = 2 * g + (ls >> 1);
                *(f16x4*)&P[w][qg][lq][(((gi ^ (lq & 7)) << 3) | ((ls & 1) << 2))] = ph;
            }
            tsum += __shfl_xor(tsum, 16, 64);
            tsum += __shfl_xor(tsum, 32, 64);
            lsum[qg] += tsum;
        }
        __builtin_amdgcn_s_setprio(1);
        #pragma unroll
        for (int c = 0; c < 2; ++c) {
            f16x8 pf[2];
            #pragma unroll
            for (int qg = 0; qg < 2; ++qg)
                pf[qg] = *(const f16x8*)&P[w][qg][lq][((4 * c + ls) ^ (lq & 7)) << 3];
            #pragma unroll
            for (int dg = 0; dg < 4; ++dg) {
                const _Float16* vp = vb + (size_t)(dg * 16 + lq) * NCTX + kbase + kv + c * 32 + ls * 8;
                f16x8 vf = *(const f16x8*)vp;
                #pragma unroll
                for (int qg = 0; qg < 2; ++qg)
                    acc[qg][dg] = mfma16(vf, pf[qg], acc[qg][dg]);
            }
        }
        __builtin_amdgcn_s_setprio(0);
    }

    #pragma unroll
    for (int qg = 0; qg < 2; ++qg) {
        const float inv = 1.f / lsum[qg];
        const int m = q0 + qg * 16 + lq;
        _Float16* rh = Ahc + (size_t)m * 1024 + hd * 64;
        _Float16* rl = Alc + (size_t)m * 1024 + hd * 64;
        #pragma unroll
        for (int dg = 0; dg < 4; ++dg) {
            f16x4 ch, cl;
            #pragma unroll
            for (int r = 0; r < 4; ++r) {
                float v = acc[qg][dg][r] * inv;
                _Float16 hh2 = (_Float16)v;
                ch[r] = hh2; cl[r] = (_Float16)(v - (float)hh2);
            }
            *(f16x4*)(rh + dg * 16 + 4 * ls) = ch;
            *(f16x4*)(rl + dg * 16 + 4 * ls) = cl;
        }
    }
}

extern "C" void kernel_launch(void* const* d_in, const int* in_sizes, int n_in,
                              void* d_out, int out_size, void* d_ws, size_t ws_size,
                              hipStream_t stream)
{
    const float* x  = (const float*)d_in[0];
    const float* Wq = (const float*)d_in[1];
    const float* bq = (const float*)d_in[2];
    const float* Wk = (const float*)d_in[3];
    const float* Wv = (const float*)d_in[4];
    const float* bv = (const float*)d_in[5];
    const float* Wo = (const float*)d_in[6];
    const float* bo = (const float*)d_in[7];
    float* out = (float*)d_out;

    char* ws = (char*)d_ws;
    _Float16* Ah  = (_Float16*)(ws + OFF_AH);
    _Float16* Al  = (_Float16*)(ws + OFF_AL);
    _Float16* Wh  = (_Float16*)(ws + OFF_WH);
    _Float16* Wl  = (_Float16*)(ws + OFF_WL);
    _Float16* Ahc = (_Float16*)(ws + OFF_AHC);
    _Float16* Alc = (_Float16*)(ws + OFF_ALC);
    _Float16* qh  = (_Float16*)(ws + OFF_QH);
    _Float16* kh  = (_Float16*)(ws + OFF_KH);
    _Float16* vt  = (_Float16*)(ws + OFF_VT);

    presplit_all<<<dim3(NCTX * 128 / 256 + 4096 * 128 / 256), 256, 0, stream>>>(
        x, Wq, Wk, Wv, Wo, Ah, Al, Wh, Wl);
    gemm32<0><<<dim3(248), 512, 0, stream>>>(ws, bq, bv, nullptr, nullptr);
    attn_kernel<<<dim3(48 * 16), 256, 0, stream>>>(qh, kh, vt, Ahc, Alc);
    gemm32<1><<<dim3(248), 512, 0, stream>>>(ws, nullptr, nullptr, bo, out);
}

// Round 9
// 204.787 us; speedup vs baseline: 1.2608x; 1.2608x over previous
//
#include <hip/hip_runtime.h>
#include <hip/hip_fp16.h>
#include <stdint.h>

#define NCTX 5952
#define NHEAD 16

typedef _Float16 f16x8 __attribute__((ext_vector_type(8)));
typedef _Float16 f16x4 __attribute__((ext_vector_type(4)));
typedef float    f32x4 __attribute__((ext_vector_type(4)));

typedef const __attribute__((address_space(1))) void* gp1;
typedef __attribute__((address_space(3))) void* lp3;

__device__ __forceinline__ f32x4 mfma16(f16x8 a, f16x8 b, f32x4 c) {
    return __builtin_amdgcn_mfma_f32_16x16x32_f16(a, b, c, 0, 0, 0);
}

// per-seq tables: lengths {512,576,640,704,768,832,896,1024}
__device__ const int kQT[9]    = {0, 4, 9, 14, 20, 26, 33, 40, 48};
__device__ const int kBASE8[8] = {0, 512, 1088, 1728, 2432, 3200, 4032, 4928};
__device__ const int kLEN[8]   = {512, 576, 640, 704, 768, 832, 896, 1024};

// ---- fused pre-split: x -> f16 hi/lo; W -> f16 hi only (B-side single f16) ----
__global__ __launch_bounds__(256) void presplit_all(
    const float* __restrict__ x,
    const float* __restrict__ Wq, const float* __restrict__ Wk,
    const float* __restrict__ Wv, const float* __restrict__ Wo,
    _Float16* __restrict__ Ah, _Float16* __restrict__ Al,
    _Float16* __restrict__ Wh)
{
    constexpr int NA = NCTX * 128 / 256;   // 2976
    const int bid = blockIdx.x;
    const float* src;
    _Float16 *dh, *dl;
    size_t off;
    if (bid < NA) {
        int idx = bid * 256 + threadIdx.x;
        int m = idx >> 7, k8 = (idx & 127) << 3;
        src = x + (size_t)m * 1024 + k8;
        off = (size_t)m * 1024 + k8;
        dh = Ah; dl = Al;
    } else {
        int idx = (bid - NA) * 256 + threadIdx.x;
        int n = idx >> 7, k8 = (idx & 127) << 3;
        const float* s = (n < 1024) ? Wq : (n < 2048) ? Wk : (n < 3072) ? Wv : Wo;
        src = s + (size_t)(n & 1023) * 1024 + k8;
        off = (size_t)n * 1024 + k8;
        dh = Wh; dl = nullptr;
    }
    f16x8 hi, lo;
    #pragma unroll
    for (int e = 0; e < 8; ++e) {
        float v = src[e];
        _Float16 h = (_Float16)v;
        hi[e] = h; lo[e] = (_Float16)(v - (float)h);
    }
    *(f16x8*)&dh[off] = hi;
    if (dl) *(f16x8*)&dl[off] = lo;
}

// ---- 2-product split GEMM: C = Ah*B + Al*B, K=1024, BK=32, T=32 ----
// BM=192; MODE 0: BN=384, grid 31x8=248 (1 round), q/k/v epilogue
//         MODE 1: BN=128, grid 31x8=248 (1 round), fp32 out + bo
// R6 carrier: 3 LDS buffers, straight-line step, ONE barrier + counted vmcnt.
// 16x16 frags with the proven 0-conflict granule swizzle (ls ^ ((r>>1)&3)).
template <int MODE>
__global__ __launch_bounds__(512) void gemm2p(
    const _Float16* __restrict__ Ahg, const _Float16* __restrict__ Alg,
    const _Float16* __restrict__ Whg,
    const float* __restrict__ bq, const float* __restrict__ bv, const float* __restrict__ bo,
    _Float16* __restrict__ qh, _Float16* __restrict__ kh, _Float16* __restrict__ vt,
    float* __restrict__ outp)
{
    constexpr int BM   = 192;
    constexpr int BN   = (MODE == 0) ? 384 : 128;
    constexpr int MI   = 6;                 // m-frags/wave (96 rows)
    constexpr int NF   = BN / 64;           // n-frags/wave (6 / 2) -> 96/32 cols
    constexpr int nB   = BN / 16;           // 24 / 8
    constexpr int SPW  = (24 + nB) / 8;     // stage instrs/wave: 6 / 4
    constexpr int ABYT = BM * 64;           // 12288
    constexpr int BBYT = BN * 64;           // 24576 / 8192
    constexpr int BUF  = 2 * ABYT + BBYT;   // 49152 / 32768
    constexpr int T    = 32;
    constexpr int W0   = (MODE == 0) ? 0 : 3072;

    __shared__ __align__(16) char lds[3 * BUF];

    int bid = blockIdx.x;
    bid = (bid & 7) * 31 + (bid >> 3);      // bijective XCD swizzle (248 = 8*31)
    const int mt = bid / 8, nt = bid % 8;
    const int m0 = mt * BM, n0 = nt * BN;
    const int tid = threadIdx.x;
    const int w = tid >> 6, l = tid & 63;
    const int ls = l >> 4, lq = l & 15;
    const int wm = w >> 2, wn = w & 3;

    // stage sources: lane fetches logical granule ((l&3) ^ ((row>>1)&3)) so the
    // LDS tile is granule-swizzled while the DMA dest stays linear (rule 21).
    const char* gsrc[SPW];
    int         ldst[SPW];
    #pragma unroll
    for (int s = 0; s < SPW; ++s) {
        int f = w * SPW + s;
        const _Float16* base; int row;
        if (f < 12)      { base = Ahg; row = m0 + f * 16; }
        else if (f < 24) { base = Alg; row = m0 + (f - 12) * 16; }
        else             { base = Whg; row = W0 + n0 + (f - 24) * 16; }
        row += (l >> 2);
        gsrc[s] = (const char*)base + (size_t)row * 2048 + 16 * ((l & 3) ^ ((row >> 1) & 3));
        ldst[s] = f * 1024;   // regions Ah|Al|Wh are contiguous in each buffer
    }
    auto STG = [&](int buf, int t2) {
        #pragma unroll
        for (int s = 0; s < SPW; ++s)
            __builtin_amdgcn_global_load_lds((gp1)(gsrc[s] + (size_t)t2 * 64),
                                             (lp3)(lds + buf * BUF + ldst[s]), 16, 0, 0);
    };

    // fragment LDS offsets; storage granule = ls ^ ((row>>1)&3)  (0-conflict, R6)
    int aoA[MI], aoB[NF];
    #pragma unroll
    for (int i = 0; i < MI; ++i) {
        int r = wm * 96 + i * 16 + lq;
        aoA[i] = r * 64 + 16 * (ls ^ ((r >> 1) & 3));
    }
    #pragma unroll
    for (int j = 0; j < NF; ++j) {
        int r = wn * (16 * NF) + j * 16 + lq;
        aoB[j] = 2 * ABYT + r * 64 + 16 * (ls ^ ((r >> 1) & 3));
    }

    f32x4 acc[MI][NF] = {};

    // prologue: stage tiles 0,1 into bufs 0,1; drain tile0, keep tile1 in flight
    STG(0, 0);
    STG(1, 1);
    if constexpr (SPW == 6) asm volatile("s_waitcnt vmcnt(6)" ::: "memory");
    else                    asm volatile("s_waitcnt vmcnt(4)" ::: "memory");
    __builtin_amdgcn_s_barrier();

    int cb = 0, pb = 2;
    #pragma unroll 1
    for (int t = 0; t < T; ++t) {
        const bool pf = (t + 2 < T);
        const char* cbp = lds + cb * BUF;
        if (pf) STG(pb, t + 2);

        f16x8 ah[MI], al[MI], b[NF];
        #pragma unroll
        for (int i = 0; i < MI; ++i) ah[i] = *(const f16x8*)(cbp + aoA[i]);
        #pragma unroll
        for (int j = 0; j < NF; ++j) b[j] = *(const f16x8*)(cbp + aoB[j]);
        __builtin_amdgcn_s_setprio(1);
        #pragma unroll
        for (int i = 0; i < MI; ++i)
            #pragma unroll
            for (int j = 0; j < NF; ++j)
                acc[i][j] = mfma16(ah[i], b[j], acc[i][j]);
        __builtin_amdgcn_s_setprio(0);
        #pragma unroll
        for (int i = 0; i < MI; ++i) al[i] = *(const f16x8*)(cbp + aoA[i] + ABYT);
        __builtin_amdgcn_s_setprio(1);
        #pragma unroll
        for (int i = 0; i < MI; ++i)
            #pragma unroll
            for (int j = 0; j < NF; ++j)
                acc[i][j] = mfma16(al[i], b[j], acc[i][j]);
        __builtin_amdgcn_s_setprio(0);

        // one sync/step: own reads drained (lgkm), tile t+1 resident (counted vm)
        if (pf) {
            if constexpr (SPW == 6) asm volatile("s_waitcnt vmcnt(6) lgkmcnt(0)" ::: "memory");
            else                    asm volatile("s_waitcnt vmcnt(4) lgkmcnt(0)" ::: "memory");
        } else {
            asm volatile("s_waitcnt vmcnt(0) lgkmcnt(0)" ::: "memory");
        }
        __builtin_amdgcn_s_barrier();
        cb = (cb == 2) ? 0 : cb + 1;
        pb = (pb == 2) ? 0 : pb + 1;
    }

    // C/D layout: col = lane&15 (-> n), row = (lane>>4)*4 + reg (-> m)
    #pragma unroll
    for (int i = 0; i < MI; ++i)
        #pragma unroll
        for (int j = 0; j < NF; ++j) {
            const int mb = m0 + wm * 96 + i * 16 + 4 * ls;
            const int n  = n0 + wn * (16 * NF) + j * 16 + lq;
            if (MODE == 0) {
                const int which = n >> 10, nn = n & 1023;
                const int hh = nn >> 6, dd = nn & 63;
                if (which == 2) {
                    f16x4 vv;
                    #pragma unroll
                    for (int r = 0; r < 4; ++r) vv[r] = (_Float16)(acc[i][j][r] + bv[nn]);
                    *(f16x4*)&vt[((size_t)hh * 64 + dd) * NCTX + mb] = vv;   // d-major
                } else if (which == 0) {
                    #pragma unroll
                    for (int r = 0; r < 4; ++r)
                        qh[((size_t)hh * NCTX + mb + r) * 64 + dd] = (_Float16)(acc[i][j][r] + bq[nn]);
                } else {
                    #pragma unroll
                    for (int r = 0; r < 4; ++r)
                        kh[((size_t)hh * NCTX + mb + r) * 64 + dd] = (_Float16)acc[i][j][r];
                }
            } else {
                #pragma unroll
                for (int r = 0; r < 4; ++r)
                    outp[(size_t)(mb + r) * 1024 + n] = acc[i][j][r] + bo[n];
            }
        }
}

// ---- flash attention (no-max), 4 waves x 32 q-rows per 128-row tile ----
__global__ __launch_bounds__(256) void attn_kernel(
    const _Float16* __restrict__ qh, const _Float16* __restrict__ kh,
    const _Float16* __restrict__ vt,
    _Float16* __restrict__ Ahc, _Float16* __restrict__ Alc)
{
    __shared__ alignas(16) _Float16 P[4][2][16][64];
    const int bid = blockIdx.x;
    const int hd = bid & 15, t = bid >> 4;
    int b = 0;
    while (t >= kQT[b + 1]) ++b;
    const int kbase = kBASE8[b];
    const int L = kLEN[b];
    const int w = threadIdx.x >> 6, l = threadIdx.x & 63;
    const int ls = l >> 4, lq = l & 15;
    const int q0l = (t - kQT[b]) * 128 + w * 32;
    if (q0l >= L) return;          // tail waves of ragged tiles; no barriers below
    const int q0 = kbase + q0l;

    f16x8 qf[2][2];
    #pragma unroll
    for (int qg = 0; qg < 2; ++qg) {
        const _Float16* qp = qh + ((size_t)hd * NCTX + q0 + qg * 16 + lq) * 64 + ls * 8;
        qf[qg][0] = *(const f16x8*)qp;
        qf[qg][1] = *(const f16x8*)(qp + 32);
    }
    const _Float16* kb = kh + (size_t)hd * NCTX * 64;
    const _Float16* vb = vt + (size_t)hd * 64 * NCTX;

    f32x4 acc[2][4] = {};
    float lsum[2] = {0.f, 0.f};

    for (int kv = 0; kv < L; kv += 64) {
        f32x4 s[2][4];
        __builtin_amdgcn_s_setprio(1);
        #pragma unroll
        for (int g = 0; g < 4; ++g) {
            const _Float16* kp = kb + (size_t)(kbase + kv + g * 16 + lq) * 64 + ls * 8;
            f16x8 kf0 = *(const f16x8*)kp;
            f16x8 kf1 = *(const f16x8*)(kp + 32);
            #pragma unroll
            for (int qg = 0; qg < 2; ++qg) {
                f32x4 z = {};
                z = mfma16(kf0, qf[qg][0], z);
                z = mfma16(kf1, qf[qg][1], z);
                s[qg][g] = z;   // S^T: row = key, col = q = lane&15
            }
        }
        __builtin_amdgcn_s_setprio(0);
        #pragma unroll
        for (int qg = 0; qg < 2; ++qg) {
            float tsum = 0.f;
            #pragma unroll
            for (int g = 0; g < 4; ++g) {
                f16x4 ph;
                #pragma unroll
                for (int r = 0; r < 4; ++r) {
                    float pv = __expf(s[qg][g][r] * 0.125f);
                    tsum += pv;
                    ph[r] = (_Float16)pv;
                }
                int gi = 2 * g + (ls >> 1);
                *(f16x4*)&P[w][qg][lq][(((gi ^ (lq & 7)) << 3) | ((ls & 1) << 2))] = ph;
            }
            tsum += __shfl_xor(tsum, 16, 64);
            tsum += __shfl_xor(tsum, 32, 64);
            lsum[qg] += tsum;
        }
        __builtin_amdgcn_s_setprio(1);
        #pragma unroll
        for (int c = 0; c < 2; ++c) {
            f16x8 pf[2];
            #pragma unroll
            for (int qg = 0; qg < 2; ++qg)
                pf[qg] = *(const f16x8*)&P[w][qg][lq][((4 * c + ls) ^ (lq & 7)) << 3];
            #pragma unroll
            for (int dg = 0; dg < 4; ++dg) {
                const _Float16* vp = vb + (size_t)(dg * 16 + lq) * NCTX + kbase + kv + c * 32 + ls * 8;
                f16x8 vf = *(const f16x8*)vp;
                #pragma unroll
                for (int qg = 0; qg < 2; ++qg)
                    acc[qg][dg] = mfma16(vf, pf[qg], acc[qg][dg]);
            }
        }
        __builtin_amdgcn_s_setprio(0);
    }

    #pragma unroll
    for (int qg = 0; qg < 2; ++qg) {
        const float inv = 1.f / lsum[qg];
        const int m = q0 + qg * 16 + lq;
        _Float16* rh = Ahc + (size_t)m * 1024 + hd * 64;
        _Float16* rl = Alc + (size_t)m * 1024 + hd * 64;
        #pragma unroll
        for (int dg = 0; dg < 4; ++dg) {
            f16x4 ch, cl;
            #pragma unroll
            for (int r = 0; r < 4; ++r) {
                float v = acc[qg][dg][r] * inv;
                _Float16 hh2 = (_Float16)v;
                ch[r] = hh2; cl[r] = (_Float16)(v - (float)hh2);
            }
            *(f16x4*)(rh + dg * 16 + 4 * ls) = ch;
            *(f16x4*)(rl + dg * 16 + 4 * ls) = cl;
        }
    }
}

extern "C" void kernel_launch(void* const* d_in, const int* in_sizes, int n_in,
                              void* d_out, int out_size, void* d_ws, size_t ws_size,
                              hipStream_t stream)
{
    const float* x  = (const float*)d_in[0];
    const float* Wq = (const float*)d_in[1];
    const float* bq = (const float*)d_in[2];
    const float* Wk = (const float*)d_in[3];
    const float* Wv = (const float*)d_in[4];
    const float* bv = (const float*)d_in[5];
    const float* Wo = (const float*)d_in[6];
    const float* bo = (const float*)d_in[7];
    float* out = (float*)d_out;

    char* p = (char*)d_ws;
    _Float16* Ah  = (_Float16*)p; p += (size_t)NCTX * 1024 * 2;
    _Float16* Al  = (_Float16*)p; p += (size_t)NCTX * 1024 * 2;
    _Float16* Wh  = (_Float16*)p; p += (size_t)4096 * 1024 * 2;
    _Float16* qh  = (_Float16*)p; p += (size_t)NHEAD * NCTX * 64 * 2;
    _Float16* kh  = (_Float16*)p; p += (size_t)NHEAD * NCTX * 64 * 2;
    _Float16* vt  = (_Float16*)p; p += (size_t)NHEAD * NCTX * 64 * 2;
    _Float16* Ahc = (_Float16*)p; p += (size_t)NCTX * 1024 * 2;
    _Float16* Alc = (_Float16*)p; p += (size_t)NCTX * 1024 * 2;

    presplit_all<<<dim3(NCTX * 128 / 256 + 4096 * 128 / 256), 256, 0, stream>>>(
        x, Wq, Wk, Wv, Wo, Ah, Al, Wh);
    gemm2p<0><<<dim3(248), 512, 0, stream>>>(Ah, Al, Wh, bq, bv, nullptr,
                                             qh, kh, vt, nullptr);
    attn_kernel<<<dim3(48 * 16), 256, 0, stream>>>(qh, kh, vt, Ahc, Alc);
    gemm2p<1><<<dim3(248), 512, 0, stream>>>(Ahc, Alc, Wh, nullptr, nullptr, bo,
                                             nullptr, nullptr, nullptr, out);
}

// Round 10
// 168.572 us; speedup vs baseline: 1.5317x; 1.2148x over previous
//
#include <hip/hip_runtime.h>
#include <hip/hip_fp16.h>
#include <stdint.h>

#define NCTX 5952
#define NHEAD 16

typedef _Float16 f16x8 __attribute__((ext_vector_type(8)));
typedef _Float16 f16x4 __attribute__((ext_vector_type(4)));
typedef float    f32x4 __attribute__((ext_vector_type(4)));

typedef const __attribute__((address_space(1))) void* gp1;
typedef __attribute__((address_space(3))) void* lp3;

__device__ __forceinline__ f32x4 mfma16(f16x8 a, f16x8 b, f32x4 c) {
    return __builtin_amdgcn_mfma_f32_16x16x32_f16(a, b, c, 0, 0, 0);
}

// per-seq tables: lengths {512,576,640,704,768,832,896,1024}
__device__ const int kQT[9]    = {0, 4, 9, 14, 20, 26, 33, 40, 48};
__device__ const int kBASE8[8] = {0, 512, 1088, 1728, 2432, 3200, 4032, 4928};
__device__ const int kLEN[8]   = {512, 576, 640, 704, 768, 832, 896, 1024};

// ---- fused pre-split: x -> f16 hi/lo; W -> f16 hi only (B-side single f16) ----
__global__ __launch_bounds__(256) void presplit_all(
    const float* __restrict__ x,
    const float* __restrict__ Wq, const float* __restrict__ Wk,
    const float* __restrict__ Wv, const float* __restrict__ Wo,
    _Float16* __restrict__ Ah, _Float16* __restrict__ Al,
    _Float16* __restrict__ Wh)
{
    constexpr int NA = NCTX * 128 / 256;   // 2976
    const int bid = blockIdx.x;
    const float* src;
    _Float16 *dh, *dl;
    size_t off;
    if (bid < NA) {
        int idx = bid * 256 + threadIdx.x;
        int m = idx >> 7, k8 = (idx & 127) << 3;
        src = x + (size_t)m * 1024 + k8;
        off = (size_t)m * 1024 + k8;
        dh = Ah; dl = Al;
    } else {
        int idx = (bid - NA) * 256 + threadIdx.x;
        int n = idx >> 7, k8 = (idx & 127) << 3;
        const float* s = (n < 1024) ? Wq : (n < 2048) ? Wk : (n < 3072) ? Wv : Wo;
        src = s + (size_t)(n & 1023) * 1024 + k8;
        off = (size_t)n * 1024 + k8;
        dh = Wh; dl = nullptr;
    }
    f16x8 hi, lo;
    #pragma unroll
    for (int e = 0; e < 8; ++e) {
        float v = src[e];
        _Float16 h = (_Float16)v;
        hi[e] = h; lo[e] = (_Float16)(v - (float)h);
    }
    *(f16x8*)&dh[off] = hi;
    if (dl) *(f16x8*)&dl[off] = lo;
}

// ---- 2-product split GEMM: C = Ah*B + Al*B, K=1024, BK=32, T=32 (R9, unchanged) ----
template <int MODE>
__global__ __launch_bounds__(512) void gemm2p(
    const _Float16* __restrict__ Ahg, const _Float16* __restrict__ Alg,
    const _Float16* __restrict__ Whg,
    const float* __restrict__ bq, const float* __restrict__ bv, const float* __restrict__ bo,
    _Float16* __restrict__ qh, _Float16* __restrict__ kh, _Float16* __restrict__ vt,
    float* __restrict__ outp)
{
    constexpr int BM   = 192;
    constexpr int BN   = (MODE == 0) ? 384 : 128;
    constexpr int MI   = 6;
    constexpr int NF   = BN / 64;
    constexpr int nB   = BN / 16;
    constexpr int SPW  = (24 + nB) / 8;     // 6 / 4
    constexpr int ABYT = BM * 64;
    constexpr int BBYT = BN * 64;
    constexpr int BUF  = 2 * ABYT + BBYT;
    constexpr int T    = 32;
    constexpr int W0   = (MODE == 0) ? 0 : 3072;

    __shared__ __align__(16) char lds[3 * BUF];

    int bid = blockIdx.x;
    bid = (bid & 7) * 31 + (bid >> 3);      // bijective XCD swizzle (248 = 8*31)
    const int mt = bid / 8, nt = bid % 8;
    const int m0 = mt * BM, n0 = nt * BN;
    const int tid = threadIdx.x;
    const int w = tid >> 6, l = tid & 63;
    const int ls = l >> 4, lq = l & 15;
    const int wm = w >> 2, wn = w & 3;

    const char* gsrc[SPW];
    int         ldst[SPW];
    #pragma unroll
    for (int s = 0; s < SPW; ++s) {
        int f = w * SPW + s;
        const _Float16* base; int row;
        if (f < 12)      { base = Ahg; row = m0 + f * 16; }
        else if (f < 24) { base = Alg; row = m0 + (f - 12) * 16; }
        else             { base = Whg; row = W0 + n0 + (f - 24) * 16; }
        row += (l >> 2);
        gsrc[s] = (const char*)base + (size_t)row * 2048 + 16 * ((l & 3) ^ ((row >> 1) & 3));
        ldst[s] = f * 1024;
    }
    auto STG = [&](int buf, int t2) {
        #pragma unroll
        for (int s = 0; s < SPW; ++s)
            __builtin_amdgcn_global_load_lds((gp1)(gsrc[s] + (size_t)t2 * 64),
                                             (lp3)(lds + buf * BUF + ldst[s]), 16, 0, 0);
    };

    int aoA[MI], aoB[NF];
    #pragma unroll
    for (int i = 0; i < MI; ++i) {
        int r = wm * 96 + i * 16 + lq;
        aoA[i] = r * 64 + 16 * (ls ^ ((r >> 1) & 3));
    }
    #pragma unroll
    for (int j = 0; j < NF; ++j) {
        int r = wn * (16 * NF) + j * 16 + lq;
        aoB[j] = 2 * ABYT + r * 64 + 16 * (ls ^ ((r >> 1) & 3));
    }

    f32x4 acc[MI][NF] = {};

    STG(0, 0);
    STG(1, 1);
    if constexpr (SPW == 6) asm volatile("s_waitcnt vmcnt(6)" ::: "memory");
    else                    asm volatile("s_waitcnt vmcnt(4)" ::: "memory");
    __builtin_amdgcn_s_barrier();

    int cb = 0, pb = 2;
    #pragma unroll 1
    for (int t = 0; t < T; ++t) {
        const bool pf = (t + 2 < T);
        const char* cbp = lds + cb * BUF;
        if (pf) STG(pb, t + 2);

        f16x8 ah[MI], al[MI], b[NF];
        #pragma unroll
        for (int i = 0; i < MI; ++i) ah[i] = *(const f16x8*)(cbp + aoA[i]);
        #pragma unroll
        for (int j = 0; j < NF; ++j) b[j] = *(const f16x8*)(cbp + aoB[j]);
        __builtin_amdgcn_s_setprio(1);
        #pragma unroll
        for (int i = 0; i < MI; ++i)
            #pragma unroll
            for (int j = 0; j < NF; ++j)
                acc[i][j] = mfma16(ah[i], b[j], acc[i][j]);
        __builtin_amdgcn_s_setprio(0);
        #pragma unroll
        for (int i = 0; i < MI; ++i) al[i] = *(const f16x8*)(cbp + aoA[i] + ABYT);
        __builtin_amdgcn_s_setprio(1);
        #pragma unroll
        for (int i = 0; i < MI; ++i)
            #pragma unroll
            for (int j = 0; j < NF; ++j)
                acc[i][j] = mfma16(al[i], b[j], acc[i][j]);
        __builtin_amdgcn_s_setprio(0);

        if (pf) {
            if constexpr (SPW == 6) asm volatile("s_waitcnt vmcnt(6) lgkmcnt(0)" ::: "memory");
            else                    asm volatile("s_waitcnt vmcnt(4) lgkmcnt(0)" ::: "memory");
        } else {
            asm volatile("s_waitcnt vmcnt(0) lgkmcnt(0)" ::: "memory");
        }
        __builtin_amdgcn_s_barrier();
        cb = (cb == 2) ? 0 : cb + 1;
        pb = (pb == 2) ? 0 : pb + 1;
    }

    #pragma unroll
    for (int i = 0; i < MI; ++i)
        #pragma unroll
        for (int j = 0; j < NF; ++j) {
            const int mb = m0 + wm * 96 + i * 16 + 4 * ls;
            const int n  = n0 + wn * (16 * NF) + j * 16 + lq;
            if (MODE == 0) {
                const int which = n >> 10, nn = n & 1023;
                const int hh = nn >> 6, dd = nn & 63;
                if (which == 2) {
                    f16x4 vv;
                    #pragma unroll
                    for (int r = 0; r < 4; ++r) vv[r] = (_Float16)(acc[i][j][r] + bv[nn]);
                    *(f16x4*)&vt[((size_t)hh * 64 + dd) * NCTX + mb] = vv;   // d-major
                } else if (which == 0) {
                    #pragma unroll
                    for (int r = 0; r < 4; ++r)
                        qh[((size_t)hh * NCTX + mb + r) * 64 + dd] = (_Float16)(acc[i][j][r] + bq[nn]);
                } else {
                    #pragma unroll
                    for (int r = 0; r < 4; ++r)
                        kh[((size_t)hh * NCTX + mb + r) * 64 + dd] = (_Float16)acc[i][j][r];
                }
            } else {
                #pragma unroll
                for (int r = 0; r < 4; ++r)
                    outp[(size_t)(mb + r) * 1024 + n] = acc[i][j][r] + bo[n];
            }
        }
}

// ---- flash attention (no-max), 4 waves x 32 q-rows per 128-row tile ----
// NEW: block-cooperative double-buffered K/V LDS staging (global_load_lds),
// granule-swizzled for conflict-free ds_read_b128; counted vmcnt; 2 barriers/step.
__global__ __launch_bounds__(256) void attn_kernel(
    const _Float16* __restrict__ qh, const _Float16* __restrict__ kh,
    const _Float16* __restrict__ vt,
    _Float16* __restrict__ Ahc, _Float16* __restrict__ Alc)
{
    __shared__ alignas(16) _Float16 KT[2][64][64];   // [buf][key][d], granule^=(key&7)
    __shared__ alignas(16) _Float16 VT[2][64][64];   // [buf][d][key], granule^=(d&7)
    __shared__ alignas(16) _Float16 P[4][2][16][64];
    const int bid = blockIdx.x;
    const int hd = bid & 15, t = bid >> 4;
    int b = 0;
    while (t >= kQT[b + 1]) ++b;
    const int kbase = kBASE8[b];
    const int L = kLEN[b];
    const int w = threadIdx.x >> 6, l = threadIdx.x & 63;
    const int ls = l >> 4, lq = l & 15;
    const int xm = lq & 7;
    const int q0l = (t - kQT[b]) * 128 + w * 32;
    const bool active = (q0l < L);       // tail waves participate in barriers only
    const int q0 = kbase + q0l;

    const _Float16* kb = kh + (size_t)hd * NCTX * 64;
    const _Float16* vb = vt + (size_t)hd * 64 * NCTX;

    // ---- staging setup: 512 granules (16B) per tile; 2 K + 2 V instrs/thread ----
    // instr s covers dest granules G = w*128 + s*64 + lane (linear LDS dest);
    // global source is the inverse-swizzled granule (rule 21).
    const char* ksrc[2]; const char* vsrc[2]; int sdst[2];
    #pragma unroll
    for (int s = 0; s < 2; ++s) {
        int G = w * 128 + s * 64 + l;
        int row = G >> 3, g = G & 7;
        ksrc[s] = (const char*)(kb + ((size_t)(kbase + row)) * 64 + (size_t)((g ^ (row & 7)) * 8));
        vsrc[s] = (const char*)(vb + (size_t)row * NCTX + kbase + (size_t)((g ^ (row & 7)) * 8));
        sdst[s] = (w * 128 + s * 64) * 16;   // wave-uniform base; HW adds lane*16
    }
    auto STG = [&](int buf, int t2) {
        #pragma unroll
        for (int s = 0; s < 2; ++s)
            __builtin_amdgcn_global_load_lds((gp1)(ksrc[s] + (size_t)t2 * 8192),
                                             (lp3)((char*)&KT[buf][0][0] + sdst[s]), 16, 0, 0);
        #pragma unroll
        for (int s = 0; s < 2; ++s)
            __builtin_amdgcn_global_load_lds((gp1)(vsrc[s] + (size_t)t2 * 128),
                                             (lp3)((char*)&VT[buf][0][0] + sdst[s]), 16, 0, 0);
    };

    f16x8 qf[2][2];
    if (active) {
        #pragma unroll
        for (int qg = 0; qg < 2; ++qg) {
            const _Float16* qp = qh + ((size_t)hd * NCTX + q0 + qg * 16 + lq) * 64 + ls * 8;
            qf[qg][0] = *(const f16x8*)qp;
            qf[qg][1] = *(const f16x8*)(qp + 32);
        }
    }

    f32x4 acc[2][4] = {};
    float lsum[2] = {0.f, 0.f};
    const int nst = L >> 6;

    STG(0, 0);
    #pragma unroll 1
    for (int tt = 0; tt < nst; ++tt) {
        const int buf = tt & 1;
        if (tt + 1 < nst) {
            STG(buf ^ 1, tt + 1);
            asm volatile("s_waitcnt vmcnt(4)" ::: "memory");
        } else {
            asm volatile("s_waitcnt vmcnt(0)" ::: "memory");
        }
        __builtin_amdgcn_s_barrier();    // buf tt staged block-wide

        if (active) {
            f32x4 s[2][4];
            __builtin_amdgcn_s_setprio(1);
            #pragma unroll
            for (int g = 0; g < 4; ++g) {
                const char* kp = (const char*)&KT[buf][g * 16 + lq][0];
                f16x8 kf0 = *(const f16x8*)(kp + ((ls ^ xm) * 16));
                f16x8 kf1 = *(const f16x8*)(kp + (((ls + 4) ^ xm) * 16));
                #pragma unroll
                for (int qg = 0; qg < 2; ++qg) {
                    f32x4 z = {};
                    z = mfma16(kf0, qf[qg][0], z);
                    z = mfma16(kf1, qf[qg][1], z);
                    s[qg][g] = z;   // S^T: row = key, col = q = lane&15
                }
            }
            __builtin_amdgcn_s_setprio(0);
            #pragma unroll
            for (int qg = 0; qg < 2; ++qg) {
                float tsum = 0.f;
                #pragma unroll
                for (int g = 0; g < 4; ++g) {
                    f16x4 ph;
                    #pragma unroll
                    for (int r = 0; r < 4; ++r) {
                        float pv = __expf(s[qg][g][r] * 0.125f);
                        tsum += pv;
                        ph[r] = (_Float16)pv;
                    }
                    int gi = 2 * g + (ls >> 1);
                    *(f16x4*)&P[w][qg][lq][(((gi ^ (lq & 7)) << 3) | ((ls & 1) << 2))] = ph;
                }
                tsum += __shfl_xor(tsum, 16, 64);
                tsum += __shfl_xor(tsum, 32, 64);
                lsum[qg] += tsum;
            }
            __builtin_amdgcn_s_setprio(1);
            #pragma unroll
            for (int c = 0; c < 2; ++c) {
                f16x8 pf[2];
                #pragma unroll
                for (int qg = 0; qg < 2; ++qg)
                    pf[qg] = *(const f16x8*)&P[w][qg][lq][((4 * c + ls) ^ (lq & 7)) << 3];
                #pragma unroll
                for (int dg = 0; dg < 4; ++dg) {
                    const char* vp = (const char*)&VT[buf][dg * 16 + lq][0];
                    f16x8 vf = *(const f16x8*)(vp + (((c * 4 + ls) ^ xm) * 16));
                    #pragma unroll
                    for (int qg = 0; qg < 2; ++qg)
                        acc[qg][dg] = mfma16(vf, pf[qg], acc[qg][dg]);
                }
            }
            __builtin_amdgcn_s_setprio(0);
        }

        // everyone's LDS reads of buf done before next staging overwrites buf^1's peer
        asm volatile("s_waitcnt lgkmcnt(0)" ::: "memory");
        __builtin_amdgcn_s_barrier();
    }

    if (active) {
        #pragma unroll
        for (int qg = 0; qg < 2; ++qg) {
            const float inv = 1.f / lsum[qg];
            const int m = q0 + qg * 16 + lq;
            _Float16* rh = Ahc + (size_t)m * 1024 + hd * 64;
            _Float16* rl = Alc + (size_t)m * 1024 + hd * 64;
            #pragma unroll
            for (int dg = 0; dg < 4; ++dg) {
                f16x4 ch, cl;
                #pragma unroll
                for (int r = 0; r < 4; ++r) {
                    float v = acc[qg][dg][r] * inv;
                    _Float16 hh2 = (_Float16)v;
                    ch[r] = hh2; cl[r] = (_Float16)(v - (float)hh2);
                }
                *(f16x4*)(rh + dg * 16 + 4 * ls) = ch;
                *(f16x4*)(rl + dg * 16 + 4 * ls) = cl;
            }
        }
    }
}

extern "C" void kernel_launch(void* const* d_in, const int* in_sizes, int n_in,
                              void* d_out, int out_size, void* d_ws, size_t ws_size,
                              hipStream_t stream)
{
    const float* x  = (const float*)d_in[0];
    const float* Wq = (const float*)d_in[1];
    const float* bq = (const float*)d_in[2];
    const float* Wk = (const float*)d_in[3];
    const float* Wv = (const float*)d_in[4];
    const float* bv = (const float*)d_in[5];
    const float* Wo = (const float*)d_in[6];
    const float* bo = (const float*)d_in[7];
    float* out = (float*)d_out;

    char* p = (char*)d_ws;
    _Float16* Ah  = (_Float16*)p; p += (size_t)NCTX * 1024 * 2;
    _Float16* Al  = (_Float16*)p; p += (size_t)NCTX * 1024 * 2;
    _Float16* Wh  = (_Float16*)p; p += (size_t)4096 * 1024 * 2;
    _Float16* qh  = (_Float16*)p; p += (size_t)NHEAD * NCTX * 64 * 2;
    _Float16* kh  = (_Float16*)p; p += (size_t)NHEAD * NCTX * 64 * 2;
    _Float16* vt  = (_Float16*)p; p += (size_t)NHEAD * NCTX * 64 * 2;
    _Float16* Ahc = (_Float16*)p; p += (size_t)NCTX * 1024 * 2;
    _Float16* Alc = (_Float16*)p; p += (size_t)NCTX * 1024 * 2;

    presplit_all<<<dim3(NCTX * 128 / 256 + 4096 * 128 / 256), 256, 0, stream>>>(
        x, Wq, Wk, Wv, Wo, Ah, Al, Wh);
    gemm2p<0><<<dim3(248), 512, 0, stream>>>(Ah, Al, Wh, bq, bv, nullptr,
                                             qh, kh, vt, nullptr);
    attn_kernel<<<dim3(48 * 16), 256, 0, stream>>>(qh, kh, vt, Ahc, Alc);
    gemm2p<1><<<dim3(248), 512, 0, stream>>>(Ahc, Alc, Wh, nullptr, nullptr, bo,
                                             nullptr, nullptr, nullptr, out);
}